// Round 9
// baseline (1842.988 us; speedup 1.0000x reference)
//
#include <hip/hip_runtime.h>

#define D 128
#define SB 256
#define SI 8
#define SCHUNK (SB * SI)

typedef __attribute__((ext_vector_type(8))) short bf16x8;
typedef __attribute__((ext_vector_type(4))) float f32x4;
typedef unsigned int uint32;
typedef unsigned short ushort;

__device__ __forceinline__ ushort bf16rne(float f) {
  uint32 u = __float_as_uint(f);
  uint32 r = u + 0x7FFFu + ((u >> 16) & 1u);
  return (ushort)(r >> 16);
}
__device__ __forceinline__ float bf2f_lo(uint32 h) { return __uint_as_float(h << 16); }
__device__ __forceinline__ float bf2f_hi(uint32 h) { return __uint_as_float(h & 0xFFFF0000u); }
__device__ __forceinline__ uint32 packbf2(float x, float y) {
  return (uint32)bf16rne(x) | ((uint32)bf16rne(y) << 16);
}

// ---------------- prep: xb convert + degree count + W-conv, one launch -----

__global__ void prep_kernel(const float* __restrict__ x, ushort* __restrict__ xb, int total4,
                            const int* __restrict__ dst, int* __restrict__ cnt, int E,
                            const float* __restrict__ W1, const float* __restrict__ W2,
                            const float* __restrict__ W3, ushort* __restrict__ Wf,
                            int xbB, int cntB) {
  int b = blockIdx.x;
  int tid = threadIdx.x;
  if (b < xbB) {
    int i = b * 256 + tid;
    if (i < total4) {
      float4 v = ((const float4*)x)[i];
      uint2 o;
      o.x = packbf2(v.x, v.y);
      o.y = packbf2(v.z, v.w);
      ((uint2*)xb)[i] = o;
    }
  } else if (b < xbB + cntB) {
    int e = (b - xbB) * 256 + tid;
    if (e < E) atomicAdd(&cnt[dst[e]], 1);
  } else {
    int idx = (b - xbB - cntB) * 256 + tid;  // 0..98303
    int which = idx >> 15;
    int id = idx & 32767;
    const float* W = (which == 0) ? W1 : ((which == 1) ? W2 : W3);
    int j = id & 7;
    int l = (id >> 3) & 63;
    int f = id >> 9;
    int p = f & 1, kc = (f >> 1) & 3, ct = f >> 3;
    int k = kc * 32 + (l >> 4) * 8 + j;
    int col = ct * 16 + (l & 15);
    float w = W[k * D + col];
    ushort hi = bf16rne(w);
    ushort outv = hi;
    if (p) {
      float hf = __uint_as_float((uint32)hi << 16);
      outv = bf16rne(w - hf);
    }
    Wf[idx] = outv;
  }
}

// ---------------- CSR build ----------------

__global__ void scan1_kernel(const int* __restrict__ cnt, int* __restrict__ off,
                             int* __restrict__ bsum, float* __restrict__ dis, int n) {
  __shared__ int tsum[SB];
  int tid = threadIdx.x;
  int base = blockIdx.x * SCHUNK;
  int v[SI];
  int s = 0;
#pragma unroll
  for (int i = 0; i < SI; i++) {
    int idx = base + tid * SI + i;
    v[i] = (idx < n) ? cnt[idx] : 0;
    s += v[i];
  }
  tsum[tid] = s;
  __syncthreads();
  for (int o = 1; o < SB; o <<= 1) {
    int t = (tid >= o) ? tsum[tid - o] : 0;
    __syncthreads();
    tsum[tid] += t;
    __syncthreads();
  }
  int run = tsum[tid] - s;
#pragma unroll
  for (int i = 0; i < SI; i++) {
    int idx = base + tid * SI + i;
    if (idx < n) {
      off[idx] = run;
      dis[idx] = rsqrtf((float)(v[i] + 1));
    }
    run += v[i];
  }
  if (tid == SB - 1) bsum[blockIdx.x] = tsum[tid];
}

// scan3: adds cross-chunk base (computed in-kernel from bsum; nb <= 64)
__global__ void scan3_kernel(int* __restrict__ off, const int* __restrict__ bsum,
                             int n, int total) {
  __shared__ int cbase;
  int b = blockIdx.x;
  int tid = threadIdx.x;
  int c = (b * 256) / SCHUNK;  // whole block lies in one chunk
  if (tid < 64) {
    int v = (tid < c) ? bsum[tid] : 0;
#pragma unroll
    for (int o = 32; o; o >>= 1) v += __shfl_down(v, o);
    if (tid == 0) cbase = v;
  }
  __syncthreads();
  int i = b * 256 + tid;
  if (i < n) off[i] += cbase;
  if (i == 0) off[n] = total;
}

// fill: cnt as countdown cursor; epack.x = src | (dstLocal<<17)  [N < 131072]
__global__ void fill_kernel(const int* __restrict__ src, const int* __restrict__ dst,
                            const int* __restrict__ off, int* __restrict__ cnt,
                            uint2* __restrict__ epack, const float* __restrict__ dis, int E) {
  int e = blockIdx.x * blockDim.x + threadIdx.x;
  if (e >= E) return;
  int s = src[e], d = dst[e];
  int slot = atomicSub(&cnt[d], 1) - 1;
  int p = off[d] + slot;
  uint2 v;
  v.x = (uint32)s | ((uint32)(d & 63) << 17);
  v.y = __float_as_uint(dis[s] * dis[d]);
  epack[p] = v;
}

// ------- fused layer: out = [relu](Agg(t) @ W + bias) ----------------------
// Edge-parallel gather: block's whole edge range strided over 16 groups,
// fp32 LDS atomic accumulation (ds_add_f32), column-permuted anti-conflict
// layout, then bf16 convert + MFMA + epilogue.

template <int FINAL>
__global__ __launch_bounds__(256, 4) void fused_kernel(const ushort* __restrict__ t,
                                                       const uint2* __restrict__ epack,
                                                       const int* __restrict__ off,
                                                       const float* __restrict__ dis,
                                                       const ushort* __restrict__ Wf,
                                                       const float* __restrict__ bias,
                                                       void* __restrict__ outp, int N) {
  __shared__ float facc[64 * 128];   // 32KB fp32 accumulator (permuted cols)
  __shared__ char tilebuf[16384];    // bf16 A-tile
  int tid = threadIdx.x;
  int row0 = blockIdx.x * 64;
  int lane = tid & 63, wv = tid >> 6;
  int q = tid & 15;       // lane-in-group
  int G = tid >> 4;       // group 0..15
  int qb = q * 16;
  const char* tb = (const char*)t;

  // zero accumulator
#pragma unroll
  for (int i = 0; i < 8; i++)
    *(f32x4*)&facc[tid * 32 + i * 4] = (f32x4){0.f, 0.f, 0.f, 0.f};
  __syncthreads();

  int rowEnd = min(row0 + 64, N);
  int eBeg = off[row0], eEnd = off[rowEnd];
  uint32 dummyx = (uint32)row0;  // src=row0, dloc=0, used with weight 0

  auto ldM = [&](int idx) -> uint2 {
    if (idx < eEnd) return epack[idx];
    uint2 z; z.x = dummyx; z.y = 0u; return z;
  };
  auto accE = [&](uint32 mx, float w, uint4 h) {
    int dl = (mx >> 17) & 63;
    int base = dl * 128;
    int sx = (dl & 3) << 3;
    float v0 = bf2f_lo(h.x), v1 = bf2f_hi(h.x);
    float v2 = bf2f_lo(h.y), v3 = bf2f_hi(h.y);
    float v4 = bf2f_lo(h.z), v5 = bf2f_hi(h.z);
    float v6 = bf2f_lo(h.w), v7 = bf2f_hi(h.w);
    atomicAdd(&facc[base + ((0 * 16 + q) ^ sx)], w * v0);
    atomicAdd(&facc[base + ((1 * 16 + q) ^ sx)], w * v1);
    atomicAdd(&facc[base + ((2 * 16 + q) ^ sx)], w * v2);
    atomicAdd(&facc[base + ((3 * 16 + q) ^ sx)], w * v3);
    atomicAdd(&facc[base + ((4 * 16 + q) ^ sx)], w * v4);
    atomicAdd(&facc[base + ((5 * 16 + q) ^ sx)], w * v5);
    atomicAdd(&facc[base + ((6 * 16 + q) ^ sx)], w * v6);
    atomicAdd(&facc[base + ((7 * 16 + q) ^ sx)], w * v7);
  };

  // edge-parallel stream: group G takes edges eBeg+G, +16, +32, ... (8-deep)
  int j = eBeg + G;
  uint2 m0 = ldM(j), m1 = ldM(j + 16), m2 = ldM(j + 32), m3 = ldM(j + 48);
  uint2 m4 = ldM(j + 64), m5 = ldM(j + 80), m6 = ldM(j + 96), m7 = ldM(j + 112);
  while (j < eEnd) {
    uint4 h0 = *(const uint4*)(tb + (((m0.x & 0x1FFFFu) << 8) + qb));
    uint4 h1 = *(const uint4*)(tb + (((m1.x & 0x1FFFFu) << 8) + qb));
    uint4 h2 = *(const uint4*)(tb + (((m2.x & 0x1FFFFu) << 8) + qb));
    uint4 h3 = *(const uint4*)(tb + (((m3.x & 0x1FFFFu) << 8) + qb));
    uint4 h4 = *(const uint4*)(tb + (((m4.x & 0x1FFFFu) << 8) + qb));
    uint4 h5 = *(const uint4*)(tb + (((m5.x & 0x1FFFFu) << 8) + qb));
    uint4 h6 = *(const uint4*)(tb + (((m6.x & 0x1FFFFu) << 8) + qb));
    uint4 h7 = *(const uint4*)(tb + (((m7.x & 0x1FFFFu) << 8) + qb));
    uint32 x0 = m0.x, x1 = m1.x, x2 = m2.x, x3 = m3.x;
    uint32 x4 = m4.x, x5 = m5.x, x6 = m6.x, x7 = m7.x;
    float w0 = __uint_as_float(m0.y), w1 = __uint_as_float(m1.y);
    float w2 = __uint_as_float(m2.y), w3 = __uint_as_float(m3.y);
    float w4 = __uint_as_float(m4.y), w5 = __uint_as_float(m5.y);
    float w6 = __uint_as_float(m6.y), w7 = __uint_as_float(m7.y);
    int jn = j + 128;
    m0 = ldM(jn); m1 = ldM(jn + 16); m2 = ldM(jn + 32); m3 = ldM(jn + 48);
    m4 = ldM(jn + 64); m5 = ldM(jn + 80); m6 = ldM(jn + 96); m7 = ldM(jn + 112);
    accE(x0, w0, h0); accE(x1, w1, h1); accE(x2, w2, h2); accE(x3, w3, h3);
    accE(x4, w4, h4); accE(x5, w5, h5); accE(x6, w6, h6); accE(x7, w7, h7);
    j = jn;
  }

  // self-loops: group G owns rows G*4..G*4+3
#pragma unroll
  for (int k = 0; k < 4; k++) {
    int r = G * 4 + k;
    int node = row0 + r;
    if (node < N) {
      uint4 hs = *(const uint4*)(tb + (((uint32)node << 8) + qb));
      float dv = dis[node];
      float sw = dv * dv;
      uint32 mx = (uint32)node | ((uint32)r << 17);
      accE(mx, sw, hs);
    }
  }
  __syncthreads();

  // convert: facc (permuted) -> bf16 tile (af layout). thread: row tid>>2, 32 cols
  {
    int r = tid >> 2, c0 = (tid & 3) * 32;
    int sx = (r & 3) << 3;
#pragma unroll
    for (int cc = 0; cc < 32; cc += 2) {
      int c = c0 + cc;
      float v0 = facc[r * 128 + ((((c & 7) * 16) + (c >> 3)) ^ sx)];
      float v1 = facc[r * 128 + (((((c + 1) & 7) * 16) + ((c + 1) >> 3)) ^ sx)];
      *(uint32*)(tilebuf + ((r * 256 + c * 2) ^ ((r & 7) << 4))) = packbf2(v0, v1);
    }
  }
  __syncthreads();

  // ---- MFMA: z(64x128) @ W(128x128), W as hi+lo bf16 ----
  int lr = lane & 15, lg = lane >> 4;
  int m0r = wv * 16;

  bf16x8 af[4];
#pragma unroll
  for (int kc = 0; kc < 4; kc++) {
    int row = m0r + lr;
    int boff = (row * 256 + kc * 64 + lg * 16) ^ ((row & 7) << 4);
    af[kc] = *(bf16x8*)(tilebuf + boff);
  }

  float bcol[8];
#pragma unroll
  for (int ct = 0; ct < 8; ct++) bcol[ct] = bias[ct * 16 + lr];

  f32x4 acc[8];
#pragma unroll
  for (int ct = 0; ct < 8; ct++) acc[ct] = (f32x4){0.f, 0.f, 0.f, 0.f};

#pragma unroll 1
  for (int ct = 0; ct < 8; ct++) {
    bf16x8 bf_[4][2];
#pragma unroll
    for (int kc = 0; kc < 4; kc++)
#pragma unroll
      for (int p = 0; p < 2; p++)
        bf_[kc][p] = *(const bf16x8*)&Wf[(size_t)((((ct * 4 + kc) * 2 + p) * 64 + lane) * 8)];
#pragma unroll
    for (int kc = 0; kc < 4; kc++) {
      acc[ct] = __builtin_amdgcn_mfma_f32_16x16x32_bf16(af[kc], bf_[kc][0], acc[ct], 0, 0, 0);
      acc[ct] = __builtin_amdgcn_mfma_f32_16x16x32_bf16(af[kc], bf_[kc][1], acc[ct], 0, 0, 0);
    }
  }
  __syncthreads();

  if (FINAL) {
    // fp32 epilogue, one pass through the 32KB facc region
    char* lds32 = (char*)facc;
#pragma unroll
    for (int ct = 0; ct < 8; ct++)
#pragma unroll
      for (int r = 0; r < 4; r++) {
        int row = m0r + lg * 4 + r;
        int col = ct * 16 + lr;
        float v = acc[ct][r] + bcol[ct];
        int boff = (row * 512 + col * 4) ^ ((row & 7) << 4);
        *(float*)(lds32 + boff) = v;
      }
    __syncthreads();
    float* out = (float*)outp;
#pragma unroll
    for (int i = 0; i < 8; i++) {
      int f = i * 4096 + tid * 16;
      int row = f >> 9;
      int boff = f ^ ((row & 7) << 4);
      if (row0 + row < N) {
        uint4 v = *(uint4*)(lds32 + boff);
        *(uint4*)((char*)out + (size_t)(row0 + row) * 512 + (f & 511)) = v;
      }
    }
  } else {
    // bf16 epilogue: bias + relu through 16KB tile
#pragma unroll
    for (int ct = 0; ct < 8; ct++)
#pragma unroll
      for (int r = 0; r < 4; r++) {
        int row = m0r + lg * 4 + r;
        int col = ct * 16 + lr;
        float v = fmaxf(acc[ct][r] + bcol[ct], 0.f);
        int boff = (row * 256 + col * 2) ^ ((row & 7) << 4);
        *(ushort*)(tilebuf + boff) = bf16rne(v);
      }
    __syncthreads();
    ushort* outb = (ushort*)outp;
#pragma unroll
    for (int i = 0; i < 4; i++) {
      int f = i * 4096 + tid * 16;
      int row = f >> 8;
      int boff = f ^ ((row & 7) << 4);
      if (row0 + row < N) {
        uint4 v = *(uint4*)(tilebuf + boff);
        *(uint4*)((char*)outb + (size_t)(row0 + row) * 256 + (f & 255)) = v;
      }
    }
  }
}

// ---------------- launch ----------------

extern "C" void kernel_launch(void* const* d_in, const int* in_sizes, int n_in,
                              void* d_out, int out_size, void* d_ws, size_t ws_size,
                              hipStream_t stream) {
  const float* x  = (const float*)d_in[0];
  const int*   ei = (const int*)d_in[1];
  const float* W1 = (const float*)d_in[2];
  const float* b1 = (const float*)d_in[3];
  const float* W2 = (const float*)d_in[4];
  const float* b2 = (const float*)d_in[5];
  const float* W3 = (const float*)d_in[6];
  const float* b3 = (const float*)d_in[7];
  int N = in_sizes[0] / D;
  int E = in_sizes[1] / 2;
  const int* srcp = ei;
  const int* dstp = ei + E;

  char* wp = (char*)d_ws;
  auto carve = [&](size_t bytes) {
    void* p = (void*)wp;
    wp += (bytes + 255) & ~(size_t)255;
    return p;
  };
  int*    cnt   = (int*)carve((size_t)N * 4);
  int*    off   = (int*)carve((size_t)(N + 1) * 4);
  int*    bsum  = (int*)carve(256 * 4);
  float*  dis   = (float*)carve((size_t)N * 4);
  uint2*  epack = (uint2*)carve((size_t)E * 8);
  ushort* xb    = (ushort*)carve((size_t)N * D * 2);
  ushort* t1    = (ushort*)carve((size_t)N * D * 2);
  ushort* t2    = (ushort*)carve((size_t)N * D * 2);
  ushort* wfall = (ushort*)carve((size_t)3 * 32768 * 2);
  ushort* wf1 = wfall, *wf2 = wfall + 32768, *wf3 = wfall + 65536;

  hipMemsetAsync(cnt, 0, (size_t)N * 4, stream);

  const int tb = 256;
  int total4 = N * D / 4;
  int xbB = (total4 + 255) / 256;
  int cntB = (E + 255) / 256;
  prep_kernel<<<xbB + cntB + 384, 256, 0, stream>>>(x, xb, total4, dstp, cnt, E,
                                                    W1, W2, W3, wfall, xbB, cntB);
  int nb = (N + SCHUNK - 1) / SCHUNK;
  scan1_kernel<<<nb, SB, 0, stream>>>(cnt, off, bsum, dis, N);
  scan3_kernel<<<(N + tb - 1) / tb, tb, 0, stream>>>(off, bsum, N, E);
  fill_kernel<<<(E + tb - 1) / tb, tb, 0, stream>>>(srcp, dstp, off, cnt, epack, dis, E);

  int fb = (N + 63) / 64;
  fused_kernel<0><<<fb, 256, 0, stream>>>(xb, epack, off, dis, wf1, b1, t1, N);
  fused_kernel<0><<<fb, 256, 0, stream>>>(t1, epack, off, dis, wf2, b2, t2, N);
  fused_kernel<1><<<fb, 256, 0, stream>>>(t2, epack, off, dis, wf3, b3, d_out, N);
}

// Round 11
// 300.822 us; speedup vs baseline: 6.1265x; 6.1265x over previous
//
#include <hip/hip_runtime.h>

#define D 128
#define SB 256
#define SI 8
#define SCHUNK (SB * SI)

typedef __attribute__((ext_vector_type(8))) short bf16x8;
typedef __attribute__((ext_vector_type(4))) float f32x4;
typedef unsigned int uint32;
typedef unsigned short ushort;

__device__ __forceinline__ ushort bf16rne(float f) {
  uint32 u = __float_as_uint(f);
  uint32 r = u + 0x7FFFu + ((u >> 16) & 1u);
  return (ushort)(r >> 16);
}
__device__ __forceinline__ float bf2f_lo(uint32 h) { return __uint_as_float(h << 16); }
__device__ __forceinline__ float bf2f_hi(uint32 h) { return __uint_as_float(h & 0xFFFF0000u); }
__device__ __forceinline__ uint32 packbf2(float x, float y) {
  return (uint32)bf16rne(x) | ((uint32)bf16rne(y) << 16);
}
__device__ __forceinline__ void acc8(float* a, float w, uint4 h) {
  a[0] += w * bf2f_lo(h.x); a[1] += w * bf2f_hi(h.x);
  a[2] += w * bf2f_lo(h.y); a[3] += w * bf2f_hi(h.y);
  a[4] += w * bf2f_lo(h.z); a[5] += w * bf2f_hi(h.z);
  a[6] += w * bf2f_lo(h.w); a[7] += w * bf2f_hi(h.w);
}

// ---------------- prep: xb convert + degree count + W-conv, one launch -----

__global__ void prep_kernel(const float* __restrict__ x, ushort* __restrict__ xb, int total4,
                            const int* __restrict__ dst, int* __restrict__ cnt, int E,
                            const float* __restrict__ W1, const float* __restrict__ W2,
                            const float* __restrict__ W3, ushort* __restrict__ Wf,
                            int xbB, int cntB) {
  int b = blockIdx.x;
  int tid = threadIdx.x;
  if (b < xbB) {
    int i = b * 256 + tid;
    if (i < total4) {
      float4 v = ((const float4*)x)[i];
      uint2 o;
      o.x = packbf2(v.x, v.y);
      o.y = packbf2(v.z, v.w);
      ((uint2*)xb)[i] = o;
    }
  } else if (b < xbB + cntB) {
    int e = (b - xbB) * 256 + tid;
    if (e < E) atomicAdd(&cnt[dst[e]], 1);
  } else {
    int idx = (b - xbB - cntB) * 256 + tid;  // 0..98303
    int which = idx >> 15;
    int id = idx & 32767;
    const float* W = (which == 0) ? W1 : ((which == 1) ? W2 : W3);
    int j = id & 7;
    int l = (id >> 3) & 63;
    int f = id >> 9;
    int p = f & 1, kc = (f >> 1) & 3, ct = f >> 3;
    int k = kc * 32 + (l >> 4) * 8 + j;
    int col = ct * 16 + (l & 15);
    float w = W[k * D + col];
    ushort hi = bf16rne(w);
    ushort outv = hi;
    if (p) {
      float hf = __uint_as_float((uint32)hi << 16);
      outv = bf16rne(w - hf);
    }
    Wf[idx] = outv;
  }
}

// ---------------- CSR build ----------------

__global__ void scan1_kernel(const int* __restrict__ cnt, int* __restrict__ off,
                             int* __restrict__ bsum, float* __restrict__ dis, int n) {
  __shared__ int tsum[SB];
  int tid = threadIdx.x;
  int base = blockIdx.x * SCHUNK;
  int v[SI];
  int s = 0;
#pragma unroll
  for (int i = 0; i < SI; i++) {
    int idx = base + tid * SI + i;
    v[i] = (idx < n) ? cnt[idx] : 0;
    s += v[i];
  }
  tsum[tid] = s;
  __syncthreads();
  for (int o = 1; o < SB; o <<= 1) {
    int t = (tid >= o) ? tsum[tid - o] : 0;
    __syncthreads();
    tsum[tid] += t;
    __syncthreads();
  }
  int run = tsum[tid] - s;
#pragma unroll
  for (int i = 0; i < SI; i++) {
    int idx = base + tid * SI + i;
    if (idx < n) {
      off[idx] = run;
      dis[idx] = rsqrtf((float)(v[i] + 1));
    }
    run += v[i];
  }
  if (tid == SB - 1) bsum[blockIdx.x] = tsum[tid];
}

// scan3: adds cross-chunk base (computed in-kernel from bsum; nb <= 64)
__global__ void scan3_kernel(int* __restrict__ off, const int* __restrict__ bsum,
                             int n, int total) {
  __shared__ int cbase;
  int b = blockIdx.x;
  int tid = threadIdx.x;
  int c = (b * 256) / SCHUNK;  // whole block lies in one chunk
  if (tid < 64) {
    int v = (tid < c) ? bsum[tid] : 0;
#pragma unroll
    for (int o = 32; o; o >>= 1) v += __shfl_down(v, o);
    if (tid == 0) cbase = v;
  }
  __syncthreads();
  int i = b * 256 + tid;
  if (i < n) off[i] += cbase;
  if (i == 0) off[n] = total;
}

// fill: uses cnt as countdown cursor (destroys it -> cnt ends all-zero)
__global__ void fill_kernel(const int* __restrict__ src, const int* __restrict__ dst,
                            const int* __restrict__ off, int* __restrict__ cnt,
                            uint2* __restrict__ epack, const float* __restrict__ dis, int E) {
  int e = blockIdx.x * blockDim.x + threadIdx.x;
  if (e >= E) return;
  int s = src[e], d = dst[e];
  int slot = atomicSub(&cnt[d], 1) - 1;
  int p = off[d] + slot;
  uint2 v;
  v.x = (uint32)s;
  v.y = __float_as_uint(dis[s] * dis[d]);
  epack[p] = v;
}

// ------- fused layer: out = [relu](Agg(t) @ W + bias) ----------------------
// gather-first (Agg commutes with @W). M=32 rows/block, 128 threads (2 waves),
// 8KB LDS -> up to 16 blocks/CU for latency-bound gather concurrency.

template <int FINAL>
__global__ __launch_bounds__(128, 8) void fused_kernel(const ushort* __restrict__ t,
                                                       const uint2* __restrict__ epack,
                                                       const int* __restrict__ off,
                                                       const float* __restrict__ dis,
                                                       const ushort* __restrict__ Wf,
                                                       const float* __restrict__ bias,
                                                       void* __restrict__ outp, int N) {
  __shared__ char lds[8192];
  int tid = threadIdx.x;
  int row0 = blockIdx.x * 32;
  int lane = tid & 63, wv = tid >> 6;  // wv 0..1
  int q = lane & 15, g = lane >> 4;
  int qb = q * 16;
  const char* tb = (const char*)t;

#pragma unroll 1
  for (int n4 = 0; n4 < 4; n4++) {
    int r = wv * 16 + n4 * 4 + g;  // 0..31
    int node = row0 + r;
    float a[8];
#pragma unroll
    for (int i = 0; i < 8; i++) a[i] = 0.f;

    if (node < N) {
      // self-loop load first (independent of edge list)
      uint4 hs = *(const uint4*)(tb + (((uint32)node << 8) + qb));
      int j0 = off[node], j1 = off[node + 1];
      float dsv = dis[node];
      float sw = dsv * dsv;

      auto ldE = [&](int idx) -> uint2 {
        if (idx < j1) return epack[idx];
        uint2 z; z.x = (uint32)node; z.y = 0u; return z;  // self row, weight 0
      };
      int j = j0;
      uint2 e0 = ldE(j), e1 = ldE(j + 1), e2 = ldE(j + 2), e3 = ldE(j + 3);
      while (j < j1) {
        uint4 h0 = *(const uint4*)(tb + ((e0.x << 8) + qb));
        uint4 h1 = *(const uint4*)(tb + ((e1.x << 8) + qb));
        uint4 h2 = *(const uint4*)(tb + ((e2.x << 8) + qb));
        uint4 h3 = *(const uint4*)(tb + ((e3.x << 8) + qb));
        float w0 = __uint_as_float(e0.y), w1 = __uint_as_float(e1.y);
        float w2 = __uint_as_float(e2.y), w3 = __uint_as_float(e3.y);
        int jn = j + 4;
        e0 = ldE(jn); e1 = ldE(jn + 1); e2 = ldE(jn + 2); e3 = ldE(jn + 3);
        acc8(a, w0, h0);
        acc8(a, w1, h1);
        acc8(a, w2, h2);
        acc8(a, w3, h3);
        j = jn;
      }
      acc8(a, sw, hs);
    }
    uint4 pv;
    pv.x = packbf2(a[0], a[1]);
    pv.y = packbf2(a[2], a[3]);
    pv.z = packbf2(a[4], a[5]);
    pv.w = packbf2(a[6], a[7]);
    int boff = (r * 256 + qb) ^ ((r & 7) << 4);
    *(uint4*)(lds + boff) = pv;
  }
  __syncthreads();

  // ---- MFMA: z(32x128) @ W(128x128), W as hi+lo bf16 ----
  int lr = lane & 15, lg = lane >> 4;
  int m0 = wv * 16;

  bf16x8 af[4];
#pragma unroll
  for (int kc = 0; kc < 4; kc++) {
    int row = m0 + lr;
    int boff = (row * 256 + kc * 64 + lg * 16) ^ ((row & 7) << 4);
    af[kc] = *(bf16x8*)(lds + boff);
  }

  float bcol[8];
#pragma unroll
  for (int ct = 0; ct < 8; ct++) bcol[ct] = bias[ct * 16 + lr];

  f32x4 acc[8];
#pragma unroll
  for (int ct = 0; ct < 8; ct++) acc[ct] = (f32x4){0.f, 0.f, 0.f, 0.f};

#pragma unroll 1
  for (int ct = 0; ct < 8; ct++) {
    bf16x8 bf_[4][2];
#pragma unroll
    for (int kc = 0; kc < 4; kc++)
#pragma unroll
      for (int p = 0; p < 2; p++)
        bf_[kc][p] = *(const bf16x8*)&Wf[(size_t)((((ct * 4 + kc) * 2 + p) * 64 + lane) * 8)];
#pragma unroll
    for (int kc = 0; kc < 4; kc++) {
      acc[ct] = __builtin_amdgcn_mfma_f32_16x16x32_bf16(af[kc], bf_[kc][0], acc[ct], 0, 0, 0);
      acc[ct] = __builtin_amdgcn_mfma_f32_16x16x32_bf16(af[kc], bf_[kc][1], acc[ct], 0, 0, 0);
    }
  }
  __syncthreads();

  if (FINAL) {
    // fp32 epilogue: two 64-column passes through 8KB LDS
    float* out = (float*)outp;
#pragma unroll
    for (int p = 0; p < 2; p++) {
#pragma unroll
      for (int c4 = 0; c4 < 4; c4++) {
        int ct = p * 4 + c4;
#pragma unroll
        for (int r = 0; r < 4; r++) {
          int row = m0 + lg * 4 + r;
          int colb = c4 * 16 + lr;  // 0..63 within pass
          float v = acc[ct][r] + bcol[ct];
          int boff = (row * 256 + colb * 4) ^ ((row & 7) << 4);
          *(float*)(lds + boff) = v;
        }
      }
      __syncthreads();
#pragma unroll
      for (int i = 0; i < 4; i++) {
        int f = i * 2048 + tid * 16;  // 128 thr x 16B x 4 = 8192B: all 32 rows
        int row = f >> 8;             // 0..31
        int boff = f ^ ((row & 7) << 4);
        if (row0 + row < N) {
          uint4 v = *(uint4*)(lds + boff);
          *(uint4*)((char*)out + (size_t)(row0 + row) * 512 + p * 256 + (f & 255)) = v;
        }
      }
      if (p == 0) __syncthreads();
    }
  } else {
    // bf16 epilogue: bias + relu through 8KB LDS
#pragma unroll
    for (int ct = 0; ct < 8; ct++)
#pragma unroll
      for (int r = 0; r < 4; r++) {
        int row = m0 + lg * 4 + r;
        int col = ct * 16 + lr;
        float v = fmaxf(acc[ct][r] + bcol[ct], 0.f);
        int boff = (row * 256 + col * 2) ^ ((row & 7) << 4);
        *(ushort*)(lds + boff) = bf16rne(v);
      }
    __syncthreads();
    ushort* outb = (ushort*)outp;
#pragma unroll
    for (int i = 0; i < 4; i++) {
      int f = i * 2048 + tid * 16;  // 128 thr x 16B x 4 = 8192B: all 32 rows
      int row = f >> 8;             // 0..31
      int boff = f ^ ((row & 7) << 4);
      if (row0 + row < N) {
        uint4 v = *(uint4*)(lds + boff);
        *(uint4*)((char*)outb + (size_t)(row0 + row) * 256 + (f & 255)) = v;
      }
    }
  }
}

// ---------------- launch ----------------

extern "C" void kernel_launch(void* const* d_in, const int* in_sizes, int n_in,
                              void* d_out, int out_size, void* d_ws, size_t ws_size,
                              hipStream_t stream) {
  const float* x  = (const float*)d_in[0];
  const int*   ei = (const int*)d_in[1];
  const float* W1 = (const float*)d_in[2];
  const float* b1 = (const float*)d_in[3];
  const float* W2 = (const float*)d_in[4];
  const float* b2 = (const float*)d_in[5];
  const float* W3 = (const float*)d_in[6];
  const float* b3 = (const float*)d_in[7];
  int N = in_sizes[0] / D;
  int E = in_sizes[1] / 2;
  const int* srcp = ei;
  const int* dstp = ei + E;

  char* wp = (char*)d_ws;
  auto carve = [&](size_t bytes) {
    void* p = (void*)wp;
    wp += (bytes + 255) & ~(size_t)255;
    return p;
  };
  int*    cnt   = (int*)carve((size_t)N * 4);
  int*    off   = (int*)carve((size_t)(N + 1) * 4);
  int*    bsum  = (int*)carve(256 * 4);
  float*  dis   = (float*)carve((size_t)N * 4);
  uint2*  epack = (uint2*)carve((size_t)E * 8);
  ushort* xb    = (ushort*)carve((size_t)N * D * 2);
  ushort* t1    = (ushort*)carve((size_t)N * D * 2);
  ushort* t2    = (ushort*)carve((size_t)N * D * 2);
  ushort* wfall = (ushort*)carve((size_t)3 * 32768 * 2);
  ushort* wf1 = wfall, *wf2 = wfall + 32768, *wf3 = wfall + 65536;

  hipMemsetAsync(cnt, 0, (size_t)N * 4, stream);

  const int tb = 256;
  int total4 = N * D / 4;
  int xbB = (total4 + 255) / 256;
  int cntB = (E + 255) / 256;
  prep_kernel<<<xbB + cntB + 384, 256, 0, stream>>>(x, xb, total4, dstp, cnt, E,
                                                    W1, W2, W3, wfall, xbB, cntB);
  int nb = (N + SCHUNK - 1) / SCHUNK;
  scan1_kernel<<<nb, SB, 0, stream>>>(cnt, off, bsum, dis, N);
  scan3_kernel<<<(N + tb - 1) / tb, tb, 0, stream>>>(off, bsum, N, E);
  fill_kernel<<<(E + tb - 1) / tb, tb, 0, stream>>>(srcp, dstp, off, cnt, epack, dis, E);

  int fb = (N + 31) / 32;
  fused_kernel<0><<<fb, 128, 0, stream>>>(xb, epack, off, dis, wf1, b1, t1, N);
  fused_kernel<0><<<fb, 128, 0, stream>>>(t1, epack, off, dis, wf2, b2, t2, N);
  fused_kernel<1><<<fb, 128, 0, stream>>>(t2, epack, off, dis, wf3, b3, d_out, N);
}

// Round 12
// 222.093 us; speedup vs baseline: 8.2983x; 1.3545x over previous
//
#include <hip/hip_runtime.h>

#define D 128
#define SB 256
#define SI 8
#define SCHUNK (SB * SI)

typedef __attribute__((ext_vector_type(8))) short bf16x8;
typedef __attribute__((ext_vector_type(4))) float f32x4;
typedef unsigned int uint32;
typedef unsigned short ushort;

__device__ __forceinline__ ushort bf16rne(float f) {
  uint32 u = __float_as_uint(f);
  uint32 r = u + 0x7FFFu + ((u >> 16) & 1u);
  return (ushort)(r >> 16);
}
__device__ __forceinline__ float bf2f_lo(uint32 h) { return __uint_as_float(h << 16); }
__device__ __forceinline__ float bf2f_hi(uint32 h) { return __uint_as_float(h & 0xFFFF0000u); }
__device__ __forceinline__ uint32 packbf2(float x, float y) {
  return (uint32)bf16rne(x) | ((uint32)bf16rne(y) << 16);
}
__device__ __forceinline__ void acc8(float* a, float w, uint4 h) {
  a[0] += w * bf2f_lo(h.x); a[1] += w * bf2f_hi(h.x);
  a[2] += w * bf2f_lo(h.y); a[3] += w * bf2f_hi(h.y);
  a[4] += w * bf2f_lo(h.z); a[5] += w * bf2f_hi(h.z);
  a[6] += w * bf2f_lo(h.w); a[7] += w * bf2f_hi(h.w);
}

// ---------------- prep: xb convert + degree count + W-conv, one launch -----

__global__ void prep_kernel(const float* __restrict__ x, ushort* __restrict__ xb, int total4,
                            const int* __restrict__ dst, int* __restrict__ cnt, int E,
                            const float* __restrict__ W1, const float* __restrict__ W2,
                            const float* __restrict__ W3, ushort* __restrict__ Wf,
                            int xbB, int cntB) {
  int b = blockIdx.x;
  int tid = threadIdx.x;
  if (b < xbB) {
    int i = b * 256 + tid;
    if (i < total4) {
      float4 v = ((const float4*)x)[i];
      uint2 o;
      o.x = packbf2(v.x, v.y);
      o.y = packbf2(v.z, v.w);
      ((uint2*)xb)[i] = o;
    }
  } else if (b < xbB + cntB) {
    int e = (b - xbB) * 256 + tid;
    if (e < E) atomicAdd(&cnt[dst[e]], 1);
  } else {
    int idx = (b - xbB - cntB) * 256 + tid;  // 0..98303
    int which = idx >> 15;
    int id = idx & 32767;
    const float* W = (which == 0) ? W1 : ((which == 1) ? W2 : W3);
    int j = id & 7;
    int l = (id >> 3) & 63;
    int f = id >> 9;
    int p = f & 1, kc = (f >> 1) & 3, ct = f >> 3;
    int k = kc * 32 + (l >> 4) * 8 + j;
    int col = ct * 16 + (l & 15);
    float w = W[k * D + col];
    ushort hi = bf16rne(w);
    ushort outv = hi;
    if (p) {
      float hf = __uint_as_float((uint32)hi << 16);
      outv = bf16rne(w - hf);
    }
    Wf[idx] = outv;
  }
}

// ---------------- CSR build ----------------

__global__ void scan1_kernel(const int* __restrict__ cnt, int* __restrict__ off,
                             int* __restrict__ bsum, float* __restrict__ dis, int n) {
  __shared__ int tsum[SB];
  int tid = threadIdx.x;
  int base = blockIdx.x * SCHUNK;
  int v[SI];
  int s = 0;
#pragma unroll
  for (int i = 0; i < SI; i++) {
    int idx = base + tid * SI + i;
    v[i] = (idx < n) ? cnt[idx] : 0;
    s += v[i];
  }
  tsum[tid] = s;
  __syncthreads();
  for (int o = 1; o < SB; o <<= 1) {
    int t = (tid >= o) ? tsum[tid - o] : 0;
    __syncthreads();
    tsum[tid] += t;
    __syncthreads();
  }
  int run = tsum[tid] - s;
#pragma unroll
  for (int i = 0; i < SI; i++) {
    int idx = base + tid * SI + i;
    if (idx < n) {
      off[idx] = run;
      dis[idx] = rsqrtf((float)(v[i] + 1));
    }
    run += v[i];
  }
  if (tid == SB - 1) bsum[blockIdx.x] = tsum[tid];
}

// scan3: adds cross-chunk base (computed in-kernel from bsum; nb <= 64)
__global__ void scan3_kernel(int* __restrict__ off, const int* __restrict__ bsum,
                             int n, int total) {
  __shared__ int cbase;
  int b = blockIdx.x;
  int tid = threadIdx.x;
  int c = (b * 256) / SCHUNK;  // whole block lies in one chunk
  if (tid < 64) {
    int v = (tid < c) ? bsum[tid] : 0;
#pragma unroll
    for (int o = 32; o; o >>= 1) v += __shfl_down(v, o);
    if (tid == 0) cbase = v;
  }
  __syncthreads();
  int i = b * 256 + tid;
  if (i < n) off[i] += cbase;
  if (i == 0) off[n] = total;
}

// fill: uses cnt as countdown cursor (destroys it -> cnt ends all-zero)
__global__ void fill_kernel(const int* __restrict__ src, const int* __restrict__ dst,
                            const int* __restrict__ off, int* __restrict__ cnt,
                            uint2* __restrict__ epack, const float* __restrict__ dis, int E) {
  int e = blockIdx.x * blockDim.x + threadIdx.x;
  if (e >= E) return;
  int s = src[e], d = dst[e];
  int slot = atomicSub(&cnt[d], 1) - 1;
  int p = off[d] + slot;
  uint2 v;
  v.x = (uint32)s;
  v.y = __float_as_uint(dis[s] * dis[d]);
  epack[p] = v;
}

// ------- fused layer: out = [relu](Agg(t) @ W + bias) ----------------------
// gather-first (Agg commutes with @W). M=32 rows/block, 128 threads (2 waves),
// 8KB LDS. launch_bounds (128,4): 128-VGPR budget -> NO spill (R11 lesson:
// (128,8) = 64-reg budget forced ~150MB of scratch spill traffic).

template <int FINAL>
__global__ __launch_bounds__(128, 4) void fused_kernel(const ushort* __restrict__ t,
                                                       const uint2* __restrict__ epack,
                                                       const int* __restrict__ off,
                                                       const float* __restrict__ dis,
                                                       const ushort* __restrict__ Wf,
                                                       const float* __restrict__ bias,
                                                       void* __restrict__ outp, int N) {
  __shared__ char lds[8192];
  int tid = threadIdx.x;
  int row0 = blockIdx.x * 32;
  int lane = tid & 63, wv = tid >> 6;  // wv 0..1
  int q = lane & 15, g = lane >> 4;
  int qb = q * 16;
  const char* tb = (const char*)t;

#pragma unroll 1
  for (int n4 = 0; n4 < 4; n4++) {
    int r = wv * 16 + n4 * 4 + g;  // 0..31
    int node = row0 + r;
    float a[8];
#pragma unroll
    for (int i = 0; i < 8; i++) a[i] = 0.f;

    if (node < N) {
      // self-loop load first (independent of edge list)
      uint4 hs = *(const uint4*)(tb + (((uint32)node << 8) + qb));
      int j0 = off[node], j1 = off[node + 1];
      float dsv = dis[node];
      float sw = dsv * dsv;

      auto ldE = [&](int idx) -> uint2 {
        if (idx < j1) return epack[idx];
        uint2 z; z.x = (uint32)node; z.y = 0u; return z;  // self row, weight 0
      };
      int j = j0;
      uint2 e0 = ldE(j), e1 = ldE(j + 1), e2 = ldE(j + 2), e3 = ldE(j + 3);
      while (j < j1) {
        uint4 h0 = *(const uint4*)(tb + ((e0.x << 8) + qb));
        uint4 h1 = *(const uint4*)(tb + ((e1.x << 8) + qb));
        uint4 h2 = *(const uint4*)(tb + ((e2.x << 8) + qb));
        uint4 h3 = *(const uint4*)(tb + ((e3.x << 8) + qb));
        float w0 = __uint_as_float(e0.y), w1 = __uint_as_float(e1.y);
        float w2 = __uint_as_float(e2.y), w3 = __uint_as_float(e3.y);
        int jn = j + 4;
        e0 = ldE(jn); e1 = ldE(jn + 1); e2 = ldE(jn + 2); e3 = ldE(jn + 3);
        acc8(a, w0, h0);
        acc8(a, w1, h1);
        acc8(a, w2, h2);
        acc8(a, w3, h3);
        j = jn;
      }
      acc8(a, sw, hs);
    }
    uint4 pv;
    pv.x = packbf2(a[0], a[1]);
    pv.y = packbf2(a[2], a[3]);
    pv.z = packbf2(a[4], a[5]);
    pv.w = packbf2(a[6], a[7]);
    int boff = (r * 256 + qb) ^ ((r & 7) << 4);
    *(uint4*)(lds + boff) = pv;
  }
  __syncthreads();

  // ---- MFMA: z(32x128) @ W(128x128), W as hi+lo bf16 ----
  int lr = lane & 15, lg = lane >> 4;
  int m0 = wv * 16;

  bf16x8 af[4];
#pragma unroll
  for (int kc = 0; kc < 4; kc++) {
    int row = m0 + lr;
    int boff = (row * 256 + kc * 64 + lg * 16) ^ ((row & 7) << 4);
    af[kc] = *(bf16x8*)(lds + boff);
  }

  float bcol[8];
#pragma unroll
  for (int ct = 0; ct < 8; ct++) bcol[ct] = bias[ct * 16 + lr];

  f32x4 acc[8];
#pragma unroll
  for (int ct = 0; ct < 8; ct++) acc[ct] = (f32x4){0.f, 0.f, 0.f, 0.f};

#pragma unroll 1
  for (int ct = 0; ct < 8; ct++) {
    bf16x8 bf_[4][2];
#pragma unroll
    for (int kc = 0; kc < 4; kc++)
#pragma unroll
      for (int p = 0; p < 2; p++)
        bf_[kc][p] = *(const bf16x8*)&Wf[(size_t)((((ct * 4 + kc) * 2 + p) * 64 + lane) * 8)];
#pragma unroll
    for (int kc = 0; kc < 4; kc++) {
      acc[ct] = __builtin_amdgcn_mfma_f32_16x16x32_bf16(af[kc], bf_[kc][0], acc[ct], 0, 0, 0);
      acc[ct] = __builtin_amdgcn_mfma_f32_16x16x32_bf16(af[kc], bf_[kc][1], acc[ct], 0, 0, 0);
    }
  }
  __syncthreads();

  if (FINAL) {
    // fp32 epilogue: two 64-column passes through 8KB LDS
    float* out = (float*)outp;
#pragma unroll
    for (int p = 0; p < 2; p++) {
#pragma unroll
      for (int c4 = 0; c4 < 4; c4++) {
        int ct = p * 4 + c4;
#pragma unroll
        for (int r = 0; r < 4; r++) {
          int row = m0 + lg * 4 + r;
          int colb = c4 * 16 + lr;  // 0..63 within pass
          float v = acc[ct][r] + bcol[ct];
          int boff = (row * 256 + colb * 4) ^ ((row & 7) << 4);
          *(float*)(lds + boff) = v;
        }
      }
      __syncthreads();
#pragma unroll
      for (int i = 0; i < 4; i++) {
        int f = i * 2048 + tid * 16;  // 128 thr x 16B x 4 = 8192B: all 32 rows
        int row = f >> 8;             // 0..31
        int boff = f ^ ((row & 7) << 4);
        if (row0 + row < N) {
          uint4 v = *(uint4*)(lds + boff);
          *(uint4*)((char*)out + (size_t)(row0 + row) * 512 + p * 256 + (f & 255)) = v;
        }
      }
      if (p == 0) __syncthreads();
    }
  } else {
    // bf16 epilogue: bias + relu through 8KB LDS
#pragma unroll
    for (int ct = 0; ct < 8; ct++)
#pragma unroll
      for (int r = 0; r < 4; r++) {
        int row = m0 + lg * 4 + r;
        int col = ct * 16 + lr;
        float v = fmaxf(acc[ct][r] + bcol[ct], 0.f);
        int boff = (row * 256 + col * 2) ^ ((row & 7) << 4);
        *(ushort*)(lds + boff) = bf16rne(v);
      }
    __syncthreads();
    ushort* outb = (ushort*)outp;
#pragma unroll
    for (int i = 0; i < 4; i++) {
      int f = i * 2048 + tid * 16;  // 128 thr x 16B x 4 = 8192B: all 32 rows
      int row = f >> 8;             // 0..31
      int boff = f ^ ((row & 7) << 4);
      if (row0 + row < N) {
        uint4 v = *(uint4*)(lds + boff);
        *(uint4*)((char*)outb + (size_t)(row0 + row) * 256 + (f & 255)) = v;
      }
    }
  }
}

// ---------------- launch ----------------

extern "C" void kernel_launch(void* const* d_in, const int* in_sizes, int n_in,
                              void* d_out, int out_size, void* d_ws, size_t ws_size,
                              hipStream_t stream) {
  const float* x  = (const float*)d_in[0];
  const int*   ei = (const int*)d_in[1];
  const float* W1 = (const float*)d_in[2];
  const float* b1 = (const float*)d_in[3];
  const float* W2 = (const float*)d_in[4];
  const float* b2 = (const float*)d_in[5];
  const float* W3 = (const float*)d_in[6];
  const float* b3 = (const float*)d_in[7];
  int N = in_sizes[0] / D;
  int E = in_sizes[1] / 2;
  const int* srcp = ei;
  const int* dstp = ei + E;

  char* wp = (char*)d_ws;
  auto carve = [&](size_t bytes) {
    void* p = (void*)wp;
    wp += (bytes + 255) & ~(size_t)255;
    return p;
  };
  int*    cnt   = (int*)carve((size_t)N * 4);
  int*    off   = (int*)carve((size_t)(N + 1) * 4);
  int*    bsum  = (int*)carve(256 * 4);
  float*  dis   = (float*)carve((size_t)N * 4);
  uint2*  epack = (uint2*)carve((size_t)E * 8);
  ushort* xb    = (ushort*)carve((size_t)N * D * 2);
  ushort* t1    = (ushort*)carve((size_t)N * D * 2);
  ushort* t2    = (ushort*)carve((size_t)N * D * 2);
  ushort* wfall = (ushort*)carve((size_t)3 * 32768 * 2);
  ushort* wf1 = wfall, *wf2 = wfall + 32768, *wf3 = wfall + 65536;

  hipMemsetAsync(cnt, 0, (size_t)N * 4, stream);

  const int tb = 256;
  int total4 = N * D / 4;
  int xbB = (total4 + 255) / 256;
  int cntB = (E + 255) / 256;
  prep_kernel<<<xbB + cntB + 384, 256, 0, stream>>>(x, xb, total4, dstp, cnt, E,
                                                    W1, W2, W3, wfall, xbB, cntB);
  int nb = (N + SCHUNK - 1) / SCHUNK;
  scan1_kernel<<<nb, SB, 0, stream>>>(cnt, off, bsum, dis, N);
  scan3_kernel<<<(N + tb - 1) / tb, tb, 0, stream>>>(off, bsum, N, E);
  fill_kernel<<<(E + tb - 1) / tb, tb, 0, stream>>>(srcp, dstp, off, cnt, epack, dis, E);

  int fb = (N + 31) / 32;
  fused_kernel<0><<<fb, 128, 0, stream>>>(xb, epack, off, dis, wf1, b1, t1, N);
  fused_kernel<0><<<fb, 128, 0, stream>>>(t1, epack, off, dis, wf2, b2, t2, N);
  fused_kernel<1><<<fb, 128, 0, stream>>>(t2, epack, off, dis, wf3, b3, d_out, N);
}